// Round 9
// baseline (184.555 us; speedup 1.0000x reference)
//
#include <hip/hip_runtime.h>
#include <stdint.h>

// ProposalLayer: top-6000 by fg score (stable), box decode+clip, greedy NMS(0.7), first 1000 kept.
#define NB 4
#define NN 262144            // 2^18 anchors per batch
#define KTOP 6000
#define NPROP 1000
#define MAXCAND 8192         // candidate cap per batch
#define MROWS 2048           // NMS mask covers first 2048 candidates (early-exit at 1000 kept)
#define NWORDS 32            // 2048/64 mask words per row
#define BOXSTRIDE 6016
#define NCHUNK 64            // chunks per batch; chunk = 4096 elements
#define NBLK (NB*NCHUNK)     // 256 blocks for k1/k3

// workspace layout (bytes)
#define GH_OFF    0                                   // 256 blocks * 128 buckets * 4 = 131072
#define THR_OFF   131072                              // 4 ints
#define CNT_OFF   131136                              // 64 ints (cnt[b*16], cacheline-padded)
#define KEYS_OFF  131584                              // NB*MAXCAND*8 = 262144
#define BOX_OFF   (KEYS_OFF + NB*MAXCAND*8)           // 393728; NB*BOXSTRIDE*16 = 385024
#define MASK_OFF  (BOX_OFF + NB*BOXSTRIDE*16)         // 778752; NB*2048*32*8 = 2097152
// sidx aliases the keys buffer (keys fully consumed into registers in k4 P1 before
// any write; block b only touches batch b's 64KB slice). stride = 16384 ints.

// Per-block private histogram of score high-bits (scores >= 0.5). No global atomics.
__global__ __launch_bounds__(256) void k1_hist(const float* __restrict__ scores,
                                               int* __restrict__ ghist_pb) {
  __shared__ int lh[128];
  int blk = blockIdx.x, b = blk >> 6, chunk = blk & 63;
  if (threadIdx.x < 128) lh[threadIdx.x] = 0;
  __syncthreads();
  const float* sc = scores + (((size_t)b * NN + (size_t)chunk * 4096) * 2);
  for (int it = 0; it < 16; ++it) {
    unsigned int bits = __float_as_uint(sc[(it * 256 + threadIdx.x) * 2 + 1]);
    if (bits >= 0x3F000000u && bits < 0x80000000u) {   // 0.5 <= s < 2 (scores in [0,1))
      int bk = (int)((bits >> 16) - 0x3F00u); if (bk > 127) bk = 127;
      atomicAdd(&lh[bk], 1);
    }
  }
  __syncthreads();
  if (threadIdx.x < 128) ghist_pb[blk * 128 + threadIdx.x] = lh[threadIdx.x];
}

// Reduce per-block hists, find per-batch threshold bucket; also zero cnt.
__global__ __launch_bounds__(128) void k2_thresh(const int* __restrict__ gh,
                                                 int* __restrict__ thr, int* __restrict__ cnt) {
  __shared__ int h[128];
  int b = blockIdx.x, t = threadIdx.x;
  int s = 0;
  for (int c = 0; c < NCHUNK; ++c) s += gh[((b << 6) + c) * 128 + t];
  h[t] = s;
  __syncthreads();
  if (t == 0) {
    int acc = 0, th = 0;
    for (int bk = 127; bk >= 0; --bk) { acc += h[bk]; if (acc >= KTOP) { th = bk; break; } }
    thr[b] = th;
    cnt[b * 16] = 0;
  }
}

// Two-phase block-local compaction: ONE global atomic per block (cacheline-padded cnt).
__global__ __launch_bounds__(256) void k3_compact(const float* __restrict__ scores,
                                                  const int* __restrict__ thr,
                                                  int* __restrict__ cnt,
                                                  unsigned long long* __restrict__ keys) {
  int blk = blockIdx.x, b = blk >> 6, chunk = blk & 63;
  int tid = threadIdx.x, lane = tid & 63, w = tid >> 6;
  const float* sc = scores + (((size_t)b * NN + (size_t)chunk * 4096) * 2);
  unsigned int thrbits = (0x3F00u + (unsigned int)thr[b]) << 16;
  unsigned long long below = (lane == 0) ? 0ULL : ((~0ULL) >> (64 - lane));
  __shared__ int woff[4];
  unsigned int bitsArr[16];
  int wcount = 0;
  for (int it = 0; it < 16; ++it) {
    unsigned int bits = __float_as_uint(sc[(it * 256 + tid) * 2 + 1]);
    bitsArr[it] = bits;
    bool pass = (bits < 0x80000000u) && (bits >= thrbits);
    wcount += (int)__popcll(__ballot(pass));           // wave-uniform
  }
  if (lane == 0) woff[w] = wcount;
  __syncthreads();
  if (tid == 0) {
    int t0 = woff[0], t1 = woff[1], t2 = woff[2], t3 = woff[3];
    int base = atomicAdd(&cnt[b * 16], t0 + t1 + t2 + t3);
    woff[0] = base; woff[1] = base + t0; woff[2] = base + t0 + t1; woff[3] = base + t0 + t1 + t2;
  }
  __syncthreads();
  int running = woff[w];
  for (int it = 0; it < 16; ++it) {
    unsigned int bits = bitsArr[it];
    bool pass = (bits < 0x80000000u) && (bits >= thrbits);
    unsigned long long act = __ballot(pass);
    if (pass) {
      int pos = running + (int)__popcll(act & below);
      if (pos < MAXCAND) {
        unsigned int n = (unsigned int)(chunk * 4096 + it * 256 + tid);
        // key: score bits desc, then index asc (matches jax.lax.top_k stability)
        keys[(b << 13) + pos] = ((unsigned long long)bits << 32) | (unsigned long long)(0xFFFFFFFFu - n);
      }
    }
    running += (int)__popcll(act);
  }
}

// Counting sort (O(n)): fine-bin by score bits above threshold, suffix-scan for
// descending positions, scatter 30-bit payloads, per-bin selection sort. Writes
// sorted source indices; gather/decode moved to k5 (96 blocks).
__global__ __launch_bounds__(1024) void k4_sort(const int* __restrict__ cnt,
                                                const unsigned long long* __restrict__ keys,
                                                const int* __restrict__ thr,
                                                int* __restrict__ sidx) {
  __shared__ unsigned int skeys[MAXCAND];   // 32 KiB payloads; [0..1023] doubles as scan temp
  __shared__ int cntb[4096];                // 16 KiB
  __shared__ int offb[4096];                // 16 KiB
  int b = blockIdx.x;
  int tid = threadIdx.x;
  int c = cnt[b * 16]; if (c > MAXCAND) c = MAXCAND;
  unsigned int thrbits = (0x3F00u + (unsigned int)thr[b]) << 16;
  unsigned int R = 0x3F800000u - thrbits;
  int bitlen = 32 - __clz((int)R);
  int shift = (bitlen > 12) ? (bitlen - 12) : 0;
  unsigned int lowmask = (shift > 0) ? ((1u << shift) - 1u) : 0u;
  for (int i = tid; i < 4096; i += 1024) cntb[i] = 0;
  __syncthreads();
  // P1: read keys, compute (bin, payload), histogram
  int bin8[8]; unsigned int pay8[8];
  #pragma unroll
  for (int i = 0; i < 8; ++i) {
    int t = i * 1024 + tid;
    bin8[i] = -1;
    if (t < c) {
      unsigned long long key = keys[(b << 13) + t];
      unsigned int sbits = (unsigned int)(key >> 32);
      unsigned int nidx  = (unsigned int)key & 0x3FFFFu;   // 0x3FFFF - idx (18-bit)
      unsigned int rel = sbits - thrbits;
      int bin = (int)(rel >> shift);
      bin8[i] = bin;
      pay8[i] = ((rel & lowmask) << 18) | nidx;            // desc payload == score desc, idx asc
      atomicAdd(&cntb[bin], 1);
    }
  }
  __syncthreads();
  // P2: suffix-sum (descending bin index) -> offb[bin] = #keys in higher bins
  unsigned int* temp = skeys;  // reuse as scan temp (overwritten in P3 after barrier)
  int lc0 = cntb[4095 - 4 * tid], lc1 = cntb[4094 - 4 * tid],
      lc2 = cntb[4093 - 4 * tid], lc3 = cntb[4092 - 4 * tid];
  int tsum = lc0 + lc1 + lc2 + lc3;
  int v = tsum;
  temp[tid] = (unsigned int)v;
  __syncthreads();
  for (int d = 1; d < 1024; d <<= 1) {
    int add = (tid >= d) ? (int)temp[tid - d] : 0;
    __syncthreads();
    v += add;
    temp[tid] = (unsigned int)v;
    __syncthreads();
  }
  int excl = v - tsum;
  offb[4095 - 4 * tid] = excl;
  offb[4094 - 4 * tid] = excl + lc0;
  offb[4093 - 4 * tid] = excl + lc0 + lc1;
  offb[4092 - 4 * tid] = excl + lc0 + lc1 + lc2;
  __syncthreads();
  // P3: scatter payloads to descending-score bin slots
  #pragma unroll
  for (int i = 0; i < 8; ++i) {
    if (bin8[i] >= 0) {
      int pos = atomicAdd(&offb[bin8[i]], 1);
      skeys[pos] = pay8[i];
    }
  }
  __syncthreads();
  // P4: per-bin selection sort (desc). offb[h] is now start+count; avg ~2.7 keys/bin.
  #pragma unroll
  for (int k = 0; k < 4; ++k) {
    int h = 4 * tid + k;
    int n = cntb[h];
    if (n > 1) {
      int base = offb[h] - n;
      for (int i = 0; i < n - 1; ++i) {
        int mx = i; unsigned int mv = skeys[base + i];
        for (int j = i + 1; j < n; ++j) {
          unsigned int vv = skeys[base + j];
          if (vv > mv) { mv = vv; mx = j; }
        }
        if (mx != i) { skeys[base + mx] = skeys[base + i]; skeys[base + i] = mv; }
      }
    }
  }
  __syncthreads();
  // P5: write sorted source indices (gather happens in k5 at high occupancy)
  for (int t = tid; t < KTOP; t += 1024) {
    int src = (t < c) ? (int)(0x3FFFFu - (skeys[t] & 0x3FFFFu)) : -1;
    sidx[(b << 14) + t] = src;
  }
}

// Gather anchors/deltas by sorted index, decode, clip. 96 blocks -> latency hidden.
__global__ __launch_bounds__(256) void k5_boxes(const float* __restrict__ deltas,
                                                const float* __restrict__ anchors,
                                                const int* __restrict__ sidx,
                                                float4* __restrict__ boxes) {
  int b = blockIdx.y;
  int cand = blockIdx.x * 256 + threadIdx.x;
  if (cand >= KTOP) return;
  int src = sidx[(b << 14) + cand];
  float4 r = make_float4(0.f, 0.f, 0.f, 0.f);
  if (src >= 0) {
    const float4* anc4 = (const float4*)anchors;
    const float4* del4 = (const float4*)deltas;
    float4 a = anc4[(size_t)b * NN + src];
    float4 d = del4[(size_t)b * NN + src];
    float d0 = d.x * 0.1f, d1 = d.y * 0.1f, d2 = d.z * 0.2f, d3 = d.w * 0.2f;
    float w = a.z - a.x, h = a.w - a.y;
    float cx = a.x + 0.5f * w, cy = a.y + 0.5f * h;
    cx += d0 * w; cy += d1 * h;
    w *= expf(d2); h *= expf(d3);
    r.x = fminf(fmaxf(cx - 0.5f * w, 0.f), 1.f);
    r.y = fminf(fmaxf(cy - 0.5f * h, 0.f), 1.f);
    r.z = fminf(fmaxf(cx + 0.5f * w, 0.f), 1.f);
    r.w = fminf(fmaxf(cy + 0.5f * h, 0.f), 1.f);
  }
  boxes[b * BOXSTRIDE + cand] = r;
}

__global__ __launch_bounds__(256) void k6_mask(const float4* __restrict__ boxes,
                                               unsigned long long* __restrict__ mask) {
  int b = blockIdx.y;
  int r0 = blockIdx.x * 64;
  __shared__ float4 rb[64];
  __shared__ float4 cb[256];
  int tid = threadIdx.x;
  if (tid < 64) rb[tid] = boxes[b * BOXSTRIDE + r0 + tid];
  __syncthreads();
  int row = tid >> 2, w = tid & 3;
  float4 R = rb[row];
  float ar = (R.z - R.x) * (R.w - R.y);
  for (int jt = 0; jt < MROWS / 256; ++jt) {
    cb[tid] = boxes[b * BOXSTRIDE + jt * 256 + tid];
    __syncthreads();
    unsigned long long bits = 0ULL;
    int cbase = w * 64;
    #pragma unroll 8
    for (int k = 0; k < 64; ++k) {
      float4 C = cb[cbase + k];
      float ac = (C.z - C.x) * (C.w - C.y);
      float lx = fmaxf(R.x, C.x), ly = fmaxf(R.y, C.y);
      float hx = fminf(R.z, C.z), hy = fminf(R.w, C.w);
      float iw = fmaxf(hx - lx, 0.f), ih = fmaxf(hy - ly, 0.f);
      float inter = iw * ih;
      if (inter > 0.7f * (ar + ac - inter + 1e-12f)) bits |= (1ULL << k);
    }
    mask[((size_t)(b * MROWS + r0 + row) << 5) + (size_t)(jt * 4 + w)] = bits;
    __syncthreads();
  }
}

// Multi-wave chunk-parallel greedy NMS. Wave 0 owns the irreducible serial
// resolve (readlane chain); the apply is spread over 256 lanes (8 rows/lane,
// partials merged into lds_supp via idempotent atomicOr); mask loads are
// prefetched one chunk ahead; loads/applies for already-resolved words skipped.
// NOTE: __builtin_amdgcn_readlane returns SIGNED int — widen via (unsigned int).
__global__ __launch_bounds__(256) void k7_scan(const unsigned long long* __restrict__ mask,
                                               const float4* __restrict__ boxes,
                                               float4* __restrict__ out) {
  int b = blockIdx.x;
  int tid = threadIdx.x;
  int wave = tid >> 6, lane = tid & 63;
  int w = tid & 31;            // owned suppression word (8 lanes per word)
  int g = tid >> 5;            // row-group 0..7: rows g+8i of each chunk
  __shared__ float4 kbox[NPROP];
  __shared__ unsigned long long lds_supp[NWORDS];
  __shared__ unsigned long long lds_keepw;
  __shared__ int lds_kept;
  const unsigned long long* M = mask + ((size_t)b * MROWS * NWORDS);
  const float4* BX = boxes + b * BOXSTRIDE;
  unsigned long long below = (lane == 0) ? 0ULL : ((~0ULL) >> (64 - lane));

  if (tid < NWORDS) lds_supp[tid] = 0ULL;
  if (tid == 0) lds_kept = 0;
  unsigned long long psupp = 0ULL;   // partial supp for word w, rows in group g
  int keptw0 = 0;                    // wave0's running kept count

  // prefetch chunk 0 (apply of chunk t feeds resolves >= t+1 -> need words w >= t+1)
  unsigned long long mrow[8];
  unsigned long long diag = 0ULL;
  float4 mybox = make_float4(0.f, 0.f, 0.f, 0.f);
  #pragma unroll
  for (int i = 0; i < 8; ++i)
    mrow[i] = (w > 0) ? M[(size_t)(g + 8 * i) * NWORDS + w] : 0ULL;
  if (wave == 0) { diag = M[(size_t)lane * NWORDS]; mybox = BX[lane]; }
  __syncthreads();                  // barrier A (init + chunk-0 state visible)

  int kept = 0;
  for (int c = 0; c < MROWS / 64; ++c) {
    // prefetch chunk c+1 (issued before resolve; in flight during serial chain)
    unsigned long long mrow_n[8] = {0ULL,0ULL,0ULL,0ULL,0ULL,0ULL,0ULL,0ULL};
    unsigned long long diag_n = 0ULL;
    float4 mybox_n = make_float4(0.f, 0.f, 0.f, 0.f);
    if (c + 1 < MROWS / 64) {
      int nb = (c + 1) * 64;
      #pragma unroll
      for (int i = 0; i < 8; ++i)
        if (w > c + 1) mrow_n[i] = M[(size_t)(nb + g + 8 * i) * NWORDS + w];
      if (wave == 0) { diag_n = M[(size_t)(nb + lane) * NWORDS + (c + 1)]; mybox_n = BX[nb + lane]; }
    }
    if (wave == 0) {
      unsigned long long suppc = lds_supp[c];
      unsigned int dlo = (unsigned int)diag, dhi = (unsigned int)(diag >> 32);
      unsigned long long keeprows = 0ULL;
      #pragma unroll
      for (int k = 0; k < 64; ++k) {
        unsigned long long dk =
            ((unsigned long long)(unsigned int)__builtin_amdgcn_readlane(dhi, k) << 32) |
            (unsigned long long)(unsigned int)__builtin_amdgcn_readlane(dlo, k);
        if (((suppc >> k) & 1ULL) == 0ULL) { keeprows |= (1ULL << k); suppc |= dk; }
      }
      bool mykeep = ((keeprows >> lane) & 1ULL) != 0ULL;
      int pos = keptw0 + (int)__popcll(keeprows & below);
      if (mykeep && pos < NPROP) { out[b * NPROP + pos] = mybox; kbox[pos] = mybox; }
      keptw0 += (int)__popcll(keeprows);
      if (lane == 0) { lds_keepw = keeprows; lds_kept = keptw0; }
    }
    __syncthreads();                // barrier B (keeprows/kept published)
    unsigned long long keeprows = lds_keepw;
    kept = lds_kept;
    #pragma unroll
    for (int i = 0; i < 8; ++i)
      if ((keeprows >> (g + 8 * i)) & 1ULL) psupp |= mrow[i];
    if (w > c) atomicOr(&lds_supp[w], psupp);   // idempotent re-OR; skip dead words
    #pragma unroll
    for (int i = 0; i < 8; ++i) mrow[i] = mrow_n[i];
    diag = diag_n; mybox = mybox_n;
    if (kept >= NPROP) break;       // uniform
    __syncthreads();                // barrier A (applies visible to next resolve)
  }

  if (wave == 0) {
    int k2 = (keptw0 > NPROP) ? NPROP : keptw0;
    // exact fallback beyond the mask window (runs only if kept<1000 after 2048)
    for (int cc = MROWS; cc < KTOP && k2 < NPROP; ++cc) {
      float4 C = BX[cc];
      float ac = (C.z - C.x) * (C.w - C.y);
      bool over = false;
      for (int j = lane; j < k2; j += 64) {
        float4 K = kbox[j];
        float ak = (K.z - K.x) * (K.w - K.y);
        float lx = fmaxf(C.x, K.x), ly = fmaxf(C.y, K.y);
        float hx = fminf(C.z, K.z), hy = fminf(C.w, K.w);
        float iw = fmaxf(hx - lx, 0.f), ih = fmaxf(hy - ly, 0.f);
        float inter = iw * ih;
        if (inter > 0.7f * (ac + ak - inter + 1e-12f)) over = true;
      }
      if (__ballot(over) == 0ULL) {
        if (lane == 0) { out[b * NPROP + k2] = C; kbox[k2] = C; }
        k2++;
      }
    }
    for (int r = k2 + lane; r < NPROP; r += 64)
      out[b * NPROP + r] = make_float4(0.f, 0.f, 0.f, 0.f);
  }
}

extern "C" void kernel_launch(void* const* d_in, const int* in_sizes, int n_in,
                              void* d_out, int out_size, void* d_ws, size_t ws_size,
                              hipStream_t stream) {
  const float* scores  = (const float*)d_in[0];
  const float* deltas  = (const float*)d_in[1];
  const float* anchors = (const float*)d_in[2];
  char* ws = (char*)d_ws;
  int* gh   = (int*)(ws + GH_OFF);
  int* thr  = (int*)(ws + THR_OFF);
  int* cnt  = (int*)(ws + CNT_OFF);
  unsigned long long* keys = (unsigned long long*)(ws + KEYS_OFF);
  int* sidx = (int*)(ws + KEYS_OFF);        // aliases keys (consumed before write)
  float4* boxes = (float4*)(ws + BOX_OFF);
  unsigned long long* mask = (unsigned long long*)(ws + MASK_OFF);
  float4* out = (float4*)d_out;

  hipLaunchKernelGGL(k1_hist,   dim3(NBLK), dim3(256),  0, stream, scores, gh);
  hipLaunchKernelGGL(k2_thresh, dim3(NB),   dim3(128),  0, stream, gh, thr, cnt);
  hipLaunchKernelGGL(k3_compact,dim3(NBLK), dim3(256),  0, stream, scores, thr, cnt, keys);
  hipLaunchKernelGGL(k4_sort,   dim3(NB),   dim3(1024), 0, stream, cnt, keys, thr, sidx);
  hipLaunchKernelGGL(k5_boxes,  dim3((KTOP + 255) / 256, NB), dim3(256), 0, stream, deltas, anchors, sidx, boxes);
  hipLaunchKernelGGL(k6_mask,   dim3(MROWS / 64, NB), dim3(256), 0, stream, boxes, mask);
  hipLaunchKernelGGL(k7_scan,   dim3(NB),   dim3(256), 0, stream, mask, boxes, out);
}